// Round 1
// baseline (206.513 us; speedup 1.0000x reference)
//
#include <hip/hip_runtime.h>

// QSoftmax (quantized softmax, 8-bit LUT) — B=8, S=2048.
//
// Key observation: with exp_zero = 1, normed_zero = 0, multiplier > 0, and
// LUT[k] = round(exp(k)) >= 1, every output element is
//   clip(round((expd-1) * (1/rowsum - 1) * mult), 0, 255)
// where (expd-1) >= 0, (1/rowsum - 1) < 0, mult > 0  =>  round(r) <= 0
// => output is identically 0.  A device-side guard verifies these
// preconditions from the real scalar/LUT inputs; if they hold we only
// stream 134 MB of zeros (write-only roofline). Otherwise a faithful
// fallback computes the full reference expression.

#define QS_S 2048   // row length (last dim)

// ws[0] (int): 1 => all-zero fold is valid, 0 => run full fallback path.
__global__ __launch_bounds__(256) void qs_guard(
    const float* __restrict__ LUT,
    const float* __restrict__ es_p, const float* __restrict__ ez_p,
    const float* __restrict__ ns_p, const float* __restrict__ nz_p,
    int* __restrict__ flag)
{
    __shared__ int ok;
    const int tid = threadIdx.x;
    if (tid == 0) ok = 1;
    __syncthreads();

    const float ez = *ez_p;
    // Per-LUT-entry conditions (256 entries, 1 per thread).
    // (a) LUT[k] >= ez  =>  a_zeroed >= 0 for any gathered element.
    // (b) S*LUT[k] > 2*ez => rowsum > 2*ez => denom = 1/rowsum < 1/ez
    //     strictly even after fp32 rounding => b_zeroed < 0 strictly
    //     (strictness also kills any inf*0 = NaN path).
    const float L = LUT[tid];
    const bool entry_ok = (L >= ez) && ((float)QS_S * L > 2.0f * ez);
    if (!entry_ok) atomicAnd(&ok, 0);

    if (tid == 0) {
        const float es = *es_p, ns = *ns_p, nz = *nz_p;
        const float mult = es * (1.0f / es) / ns;   // same fp32 op order as ref
        // mult > 0: product term is <= 0 (never NaN given strict b_zeroed<0).
        // nz < 0.5: round(r) <= round(nz) <= 0  => clip(...,0,255) == 0.
        const bool s_ok = (ez > 0.0f) && (mult > 0.0f) && (nz < 0.5f);
        if (!s_ok) atomicAnd(&ok, 0);
    }
    __syncthreads();
    if (tid == 0) *flag = ok;
}

// One block per row (B*S = 16384 rows). Zero path: 2 float4 stores/thread.
// Fallback: full reference computation for the row.
__global__ __launch_bounds__(256) void qs_main(
    const int*   __restrict__ inp,
    const float* __restrict__ LUT,
    const float* __restrict__ es_p, const float* __restrict__ ez_p,
    const float* __restrict__ ns_p, const float* __restrict__ nz_p,
    float* __restrict__ out,
    const int* __restrict__ flag)
{
    const int tid = threadIdx.x;
    const long base = (long)blockIdx.x * QS_S;
    float4* __restrict__ outv = (float4*)(out + base);

    if (*flag) {
        // All-zero fold: write-only streaming, fully coalesced.
        const float4 z = make_float4(0.f, 0.f, 0.f, 0.f);
        outv[tid]        = z;
        outv[tid + 256]  = z;
        return;
    }

    // ---------- faithful fallback (reference semantics) ----------
    __shared__ float lut_s[256];
    __shared__ float wsum[4];
    lut_s[tid] = LUT[tid];
    __syncthreads();

    const int4* __restrict__ iv = (const int4*)(inp + base);
    const int4 a0 = iv[tid];
    const int4 a1 = iv[tid + 256];

    // JAX gather clamps out-of-range indices.
    auto lu = [&](int v) -> float {
        v = v < 0 ? 0 : (v > 255 ? 255 : v);
        return lut_s[v];
    };
    const float e0 = lu(a0.x), e1 = lu(a0.y), e2 = lu(a0.z), e3 = lu(a0.w);
    const float e4 = lu(a1.x), e5 = lu(a1.y), e6 = lu(a1.z), e7 = lu(a1.w);

    // Row sum (fp32).
    float s = ((e0 + e1) + (e2 + e3)) + ((e4 + e5) + (e6 + e7));
    #pragma unroll
    for (int off = 32; off > 0; off >>= 1) s += __shfl_down(s, off);
    if ((tid & 63) == 0) wsum[tid >> 6] = s;
    __syncthreads();
    const float total = (wsum[0] + wsum[1]) + (wsum[2] + wsum[3]);

    const float es = *es_p, ez = *ez_p, ns = *ns_p, nz = *nz_p;
    const float denom = 1.0f / total;
    const float bz    = denom - 1.0f / ez;
    const float mult  = es * (1.0f / es) / ns;

    auto qm = [&](float e) -> float {
        const float r = (e - ez) * bz * mult + nz;
        return fminf(fmaxf(rintf(r), 0.0f), 255.0f);  // rintf = half-to-even, as jnp.round
    };
    outv[tid]       = make_float4(qm(e0), qm(e1), qm(e2), qm(e3));
    outv[tid + 256] = make_float4(qm(e4), qm(e5), qm(e6), qm(e7));
}

extern "C" void kernel_launch(void* const* d_in, const int* in_sizes, int n_in,
                              void* d_out, int out_size, void* d_ws, size_t ws_size,
                              hipStream_t stream) {
    const int*   inp = (const int*)  d_in[0];
    const float* LUT = (const float*)d_in[1];
    const float* es  = (const float*)d_in[2];
    const float* ez  = (const float*)d_in[3];
    const float* ns  = (const float*)d_in[4];
    const float* nz  = (const float*)d_in[5];
    float* out = (float*)d_out;
    int*   flag = (int*)d_ws;

    const int rows = in_sizes[0] / QS_S;   // B*S = 16384

    qs_guard<<<1, 256, 0, stream>>>(LUT, es, ez, ns, nz, flag);
    qs_main<<<rows, 256, 0, stream>>>(inp, LUT, es, ez, ns, nz, out, flag);
}